// Round 19
// baseline (61.798 us; speedup 1.0000x reference)
//
#include <hip/hip_runtime.h>
#include <math.h>

#define N_NODE 10
#define N_FEAT 8
#define HID 80
#define IN_DIM 40

typedef __attribute__((ext_vector_type(8))) short bf16x8;
typedef __attribute__((ext_vector_type(4))) float f32x4;
typedef __attribute__((ext_vector_type(4))) unsigned uint4v;

#define NF2   9           // layer-2 fragments kept in LDS (1KB each)
#define TILEB 2560        // 16 rows x 160B, contiguous in x / out

// Manual RNE fp32->bf16 (setup kernel only; finite inputs).
__device__ __forceinline__ short f2bf(float f) {
    unsigned u = __builtin_bit_cast(unsigned, f);
    u += 0x7fffu + ((u >> 16) & 1u);
    return (short)(u >> 16);
}

// HW packed convert: lo->bits[15:0], hi->bits[31:16], RNE. Register-only asm.
__device__ __forceinline__ unsigned cvtpk(float lo, float hi) {
    unsigned r;
    asm("v_cvt_pk_bf16_f32 %0, %1, %2" : "=v"(r) : "v"(lo), "v"(hi));
    return r;
}

// Compiler-level memory fence (TBAA-proof ordering, zero runtime cost).
__device__ __forceinline__ void memfence_compiler() {
    asm volatile("" ::: "memory");
}

// Async 16B/lane global->LDS; LDS dest = wave-uniform base + lane*16.
__device__ __forceinline__ void gload16(const void* gsrc, void* ldst) {
    __builtin_amdgcn_global_load_lds(
        (const __attribute__((address_space(1))) unsigned*)gsrc,
        (__attribute__((address_space(3))) unsigned*)ldst, 16, 0, 0);
}

// ws layout (floats): [0,...) packed frags only
#define FRAG_OFF 0

// ---------------------------------------------------------------------------
// PARALLEL setup: 19 blocks x 64 threads; block fid packs exactly fragment
// fid (1KB). Wf1 blocks gather W_enc/b_enc directly. Wf2 blocks compute ONLY
// the W_mid rows their fragment needs (<=512 elems, redundant per block, into
// LDS scratch; same fmaf order as before -> bit-identical results) and pack.
//   Wf1[t][s] lane(m,q) elem e : k=32s+8q+e              -> W_enc[k][16t+m], k==40 -> b_enc
//   Wf2[t][s] lane(m,q) elem e : n=32s+16(e>>2)+4q+(e&3) -> W_mid[n][16t+m], n==80 -> b_mid
// ---------------------------------------------------------------------------
__global__ void setup_kernel(const float* __restrict__ W_enc,
                             const float* __restrict__ b_enc,
                             const float* __restrict__ W_rel,
                             const float* __restrict__ b_rel,
                             const float* __restrict__ W_root,
                             const float* __restrict__ W_dec,
                             const float* __restrict__ b_dec,
                             float* __restrict__ ws)
{
    const int fid  = blockIdx.x;           // 0..18
    const int lane = threadIdx.x;          // 64 threads
    const int m = lane & 15;
    const int q = lane >> 4;
    unsigned* fb = (unsigned*)(ws + FRAG_OFF);

    if (fid < 10) {
        // ---- layer-1 fragment: direct gather from W_enc / b_enc ----
        const int t = fid >> 1, s = fid & 1;
        short v[8];
        #pragma unroll
        for (int e = 0; e < 8; ++e) {
            const int k = 32 * s + 8 * q + e;
            float f = 0.0f;
            if (k < IN_DIM)       f = W_enc[k * HID + 16 * t + m];
            else if (k == IN_DIM) f = b_enc[16 * t + m];
            v[e] = f2bf(f);
        }
        #pragma unroll
        for (int j = 0; j < 4; ++j)
            fb[fid * 256 + lane * 4 + j] =
                (unsigned)(unsigned short)v[2 * j] |
                ((unsigned)(unsigned short)v[2 * j + 1] << 16);
        return;
    }

    // ---- layer-2 fragment: compute needed W_mid rows, then pack ----
    const int t2 = (fid - 10) / 3;
    const int s  = (fid - 10) % 3;
    const int n0 = 32 * s;                       // first n row needed
    const int ncnt = (s < 2) ? 32 : 16;          // rows needed (s=2: 64..79)
    const int obase = 16 * t2;

    __shared__ float wm[33][16];                 // rows [0,ncnt) + bias row 32
    const float w = expf(-1.0f / 9.0f);

    for (int i = lane; i < ncnt * 16; i += 64) {
        const int nn = i >> 4;
        const int oo = i & 15;
        const int n  = n0 + nn;
        const int o  = obase + oo;
        float acc = 0.0f;
        if (o < IN_DIM) {
            const int sn = n / N_FEAT;
            const int f  = n % N_FEAT;
            const int sp = (sn + 1) % N_NODE;
            const int sm_ = (sn + N_NODE - 1) % N_NODE;
            #pragma unroll
            for (int g = 0; g < N_FEAT; ++g) {
                acc = fmaf(W_root[f * N_FEAT + g], W_dec[(sn * N_FEAT + g) * IN_DIM + o], acc);
                acc = fmaf(w * W_rel[f * N_FEAT + g],
                           W_dec[(sp * N_FEAT + g) * IN_DIM + o] +
                           W_dec[(sm_ * N_FEAT + g) * IN_DIM + o], acc);
            }
        }
        wm[nn][oo] = acc;
    }
    if (s == 2) {
        for (int i = lane; i < 16; i += 64) {
            const int o = obase + i;
            float acc = 0.0f;
            if (o < IN_DIM) {
                acc = b_dec[o];
                #pragma unroll
                for (int t = 0; t < N_NODE; ++t)
                    #pragma unroll
                    for (int g = 0; g < N_FEAT; ++g)
                        acc = fmaf(b_rel[g], W_dec[(t * N_FEAT + g) * IN_DIM + o], acc);
            }
            wm[32][i] = acc;
        }
    }
    __syncthreads();

    short v[8];
    #pragma unroll
    for (int e = 0; e < 8; ++e) {
        const int n = 32 * s + 16 * (e >> 2) + 4 * q + (e & 3);
        float f = 0.0f;
        if (obase + m < IN_DIM) {
            if (n < HID) {
                const int nn = n - n0;           // in [0, ncnt) by construction
                f = wm[nn][m];
            } else if (n == HID) {
                f = wm[32][m];
            }
        }
        v[e] = f2bf(f);
    }
    #pragma unroll
    for (int j = 0; j < 4; ++j)
        fb[fid * 256 + lane * 4 + j] =
            (unsigned)(unsigned short)v[2 * j] |
            ((unsigned)(unsigned short)v[2 * j + 1] << 16);
}

// ---------------------------------------------------------------------------
// Fused MLP (verified optimum, R17): async direct-to-LDS staging
// (global_load_lds, no VGPR round trip), double-buffered linear x-strips,
// depth-1 counted vmcnt(3) with a full iteration of slack between issue and
// first use (depth-2 proved unsafe: mixed LDS-DMA + store retirement in one
// counter does not identify which group completed), Wf1 in registers / Wf2
// in LDS, fully-coalesced 1KB global ops both directions, NONTEMPORAL out
// stores (zero-reuse write stream bypasses cache allocation, preserving
// L2/L3 for x).
// ---------------------------------------------------------------------------
__global__ __launch_bounds__(256, 8) void fused_mfma_kernel(
    const float* __restrict__ x,
    const float* __restrict__ ws,
    float* __restrict__ out,
    int B, int ntiles)
{
    __shared__ uint4v wlds[NF2 * 64];                       // 9216 B (Wf2)
    __shared__ __align__(16) char xstrip[4][2][TILEB];      // 20480 B

    const int tid  = threadIdx.x;
    const int wave = tid >> 6;
    const int lane = tid & 63;
    const int m = lane & 15;
    const int q = lane >> 4;

    const uint4v* fb = (const uint4v*)(ws + FRAG_OFF);

    // ---- block prologue: stage Wf2 fragments into LDS ----
    for (int i = tid; i < NF2 * 64; i += 256)
        wlds[i] = fb[10 * 64 + i];
    __syncthreads();

    // ---- per-wave prologue: Wf1 fragments into registers (10 x dwordx4) ----
    bf16x8 Wf1[5][2];
    #pragma unroll
    for (int t = 0; t < 5; ++t)
        #pragma unroll
        for (int s = 0; s < 2; ++s)
            Wf1[t][s] = __builtin_bit_cast(bf16x8, fb[(t * 2 + s) * 64 + lane]);

    char* bufA = xstrip[wave][0];
    char* bufB = xstrip[wave][1];
    const uint4v* wl = wlds + lane;                         // Wf2 frag j at wl[j*64]
    const char* xptr = (const char*)x;
    char* optr = (char*)out;
    const size_t xbytes = (size_t)B * (IN_DIM * 4);

    const int gb0 = lane * 16, gb1 = gb0 + 1024, gb2 = gb0 + 2048;
    const bool has2 = (lane < 32);
    const int xrow = 160 * m;                               // row base in strip

    const int nw = gridDim.x * 4;
    int it = blockIdx.x * 4 + wave;
    if (it >= ntiles) return;

    // ---- prologue: async-stage tile `it` into bufA, full drain once ----
    {
        const char* src = xptr + (size_t)it * TILEB;
        gload16(src + gb0, bufA);
        gload16(src + gb1, bufA + 1024);
        if (has2) gload16(src + gb2, bufA + 2048);
    }
    asm volatile("s_waitcnt vmcnt(0)" ::: "memory");
    __builtin_amdgcn_sched_barrier(0);

    char* cb = bufA;        // current tile's buffer
    char* nb = bufB;        // next tile's buffer

    while (true) {
        const int itn = it + nw;

        // ---- W: counted wait — current tile's 3 gloads are the oldest
        //      outstanding VMEM; prior stores (newer) may stay in flight ----
        asm volatile("s_waitcnt vmcnt(3)" ::: "memory");
        __builtin_amdgcn_sched_barrier(0);

        // ---- A: issue async staging of next tile into the other buffer ----
        if (itn < ntiles) {
            const char* src = xptr + (size_t)itn * TILEB;
            gload16(src + gb0, nb);
            gload16(src + gb1, nb + 1024);
            if (has2) gload16(src + gb2, nb + 2048);
        }

        // ---- B: x fragments from cb (row m = bytes 160m..160m+159) ----
        const f32x4 xa = __builtin_bit_cast(f32x4, *(const uint4v*)(cb + xrow + 32 * q));
        const f32x4 xb = __builtin_bit_cast(f32x4, *(const uint4v*)(cb + xrow + 32 * q + 16));
        uint4v xu0;
        xu0.x = cvtpk(xa[0], xa[1]); xu0.y = cvtpk(xa[2], xa[3]);
        xu0.z = cvtpk(xb[0], xb[1]); xu0.w = cvtpk(xb[2], xb[3]);
        uint4v xu1;
        if (q == 0) {
            const f32x4 xc = __builtin_bit_cast(f32x4, *(const uint4v*)(cb + xrow + 128));
            const f32x4 xd = __builtin_bit_cast(f32x4, *(const uint4v*)(cb + xrow + 144));
            xu1.x = cvtpk(xc[0], xc[1]); xu1.y = cvtpk(xc[2], xc[3]);
            xu1.z = cvtpk(xd[0], xd[1]); xu1.w = cvtpk(xd[2], xd[3]);
        } else {
            xu1.x = (q == 1) ? 0x3F80u : 0u;   // 1.0 at bias k-slot 40
            xu1.y = 0u; xu1.z = 0u; xu1.w = 0u;
        }
        const bf16x8 X0 = __builtin_bit_cast(bf16x8, xu0);
        const bf16x8 X1 = __builtin_bit_cast(bf16x8, xu1);

        // layer 1 (swapped, reg weights): lane gets y[m][16t+4q+r]
        f32x4 acc1[5];
        #pragma unroll
        for (int t = 0; t < 5; ++t) { acc1[t][0]=0.f; acc1[t][1]=0.f; acc1[t][2]=0.f; acc1[t][3]=0.f; }
        #pragma unroll
        for (int t = 0; t < 5; ++t) {
            acc1[t] = __builtin_amdgcn_mfma_f32_16x16x32_bf16(Wf1[t][0], X0, acc1[t], 0, 0, 0);
            acc1[t] = __builtin_amdgcn_mfma_f32_16x16x32_bf16(Wf1[t][1], X1, acc1[t], 0, 0, 0);
        }

        // relu + packed repack: layer-2 B-fragment IS acc1 under the k-map
        float r0, r1;
        uint4v pu0, pu1, pu2;
        r0 = fmaxf(acc1[0][0], 0.f); r1 = fmaxf(acc1[0][1], 0.f); pu0.x = cvtpk(r0, r1);
        r0 = fmaxf(acc1[0][2], 0.f); r1 = fmaxf(acc1[0][3], 0.f); pu0.y = cvtpk(r0, r1);
        r0 = fmaxf(acc1[1][0], 0.f); r1 = fmaxf(acc1[1][1], 0.f); pu0.z = cvtpk(r0, r1);
        r0 = fmaxf(acc1[1][2], 0.f); r1 = fmaxf(acc1[1][3], 0.f); pu0.w = cvtpk(r0, r1);
        r0 = fmaxf(acc1[2][0], 0.f); r1 = fmaxf(acc1[2][1], 0.f); pu1.x = cvtpk(r0, r1);
        r0 = fmaxf(acc1[2][2], 0.f); r1 = fmaxf(acc1[2][3], 0.f); pu1.y = cvtpk(r0, r1);
        r0 = fmaxf(acc1[3][0], 0.f); r1 = fmaxf(acc1[3][1], 0.f); pu1.z = cvtpk(r0, r1);
        r0 = fmaxf(acc1[3][2], 0.f); r1 = fmaxf(acc1[3][3], 0.f); pu1.w = cvtpk(r0, r1);
        r0 = fmaxf(acc1[4][0], 0.f); r1 = fmaxf(acc1[4][1], 0.f); pu2.x = cvtpk(r0, r1);
        r0 = fmaxf(acc1[4][2], 0.f); r1 = fmaxf(acc1[4][3], 0.f); pu2.y = cvtpk(r0, r1);
        pu2.z = (q == 0) ? 0x3F80u : 0u;       // 1.0 at bias n-slot 80
        pu2.w = 0u;
        const bf16x8 P0 = __builtin_bit_cast(bf16x8, pu0);
        const bf16x8 P1 = __builtin_bit_cast(bf16x8, pu1);
        const bf16x8 P2 = __builtin_bit_cast(bf16x8, pu2);

        // layer 2 (swapped, LDS weights): lane gets out[m][16t+4q+r]
        f32x4 acc2[3];
        #pragma unroll
        for (int t = 0; t < 3; ++t) { acc2[t][0]=0.f; acc2[t][1]=0.f; acc2[t][2]=0.f; acc2[t][3]=0.f; }
        #pragma unroll
        for (int t = 0; t < 3; ++t) {
            const bf16x8 w0 = __builtin_bit_cast(bf16x8, wl[(t * 3 + 0) * 64]);
            acc2[t] = __builtin_amdgcn_mfma_f32_16x16x32_bf16(w0, P0, acc2[t], 0, 0, 0);
            const bf16x8 w1 = __builtin_bit_cast(bf16x8, wl[(t * 3 + 1) * 64]);
            acc2[t] = __builtin_amdgcn_mfma_f32_16x16x32_bf16(w1, P1, acc2[t], 0, 0, 0);
            const bf16x8 w2 = __builtin_bit_cast(bf16x8, wl[(t * 3 + 2) * 64]);
            acc2[t] = __builtin_amdgcn_mfma_f32_16x16x32_bf16(w2, P2, acc2[t], 0, 0, 0);
        }
        memfence_compiler();

        // ---- C: relu + scatter out-tile into cb (row m, cols 16t+4q..) ----
        #pragma unroll
        for (int t = 0; t < 3; ++t) {
            const int o0 = 16 * t + 4 * q;
            if (o0 < IN_DIM) {
                f32x4 v;
                v[0] = fmaxf(acc2[t][0], 0.f);
                v[1] = fmaxf(acc2[t][1], 0.f);
                v[2] = fmaxf(acc2[t][2], 0.f);
                v[3] = fmaxf(acc2[t][3], 0.f);
                *(uint4v*)(cb + xrow + 4 * o0) = __builtin_bit_cast(uint4v, v);
            }
        }
        memfence_compiler();

        // ---- D: linear readback + coalesced 1KB NONTEMPORAL stores ----
        {
            const size_t ob = (size_t)it * TILEB;
            const uint4v s0 = *(const uint4v*)(cb + gb0);
            const uint4v s1 = *(const uint4v*)(cb + gb1);
            if (ob + gb0 + 16 <= xbytes)
                __builtin_nontemporal_store(s0, (uint4v*)(optr + ob + gb0));
            if (ob + gb1 + 16 <= xbytes)
                __builtin_nontemporal_store(s1, (uint4v*)(optr + ob + gb1));
            if (has2) {
                const uint4v s2 = *(const uint4v*)(cb + gb2);
                if (ob + gb2 + 16 <= xbytes)
                    __builtin_nontemporal_store(s2, (uint4v*)(optr + ob + gb2));
            }
        }
        memfence_compiler();

        if (itn >= ntiles) break;
        { char* tmp = cb; cb = nb; nb = tmp; }
        it = itn;
    }
}

extern "C" void kernel_launch(void* const* d_in, const int* in_sizes, int n_in,
                              void* d_out, int out_size, void* d_ws, size_t ws_size,
                              hipStream_t stream)
{
    const float* x      = (const float*)d_in[0];
    const float* W_enc  = (const float*)d_in[1];
    const float* b_enc  = (const float*)d_in[2];
    const float* W_rel  = (const float*)d_in[3];
    const float* b_rel  = (const float*)d_in[4];
    const float* W_root = (const float*)d_in[5];
    const float* W_dec  = (const float*)d_in[6];
    const float* b_dec  = (const float*)d_in[7];
    float* out = (float*)d_out;

    const int B = in_sizes[0] / IN_DIM;
    const int ntiles = (B + 15) / 16;

    float* ws = (float*)d_ws;

    // Parallel setup: 19 blocks, one 1KB fragment each (~2-3 us wall).
    setup_kernel<<<19, 64, 0, stream>>>(W_enc, b_enc, W_rel, b_rel, W_root,
                                        W_dec, b_dec, ws);

    // Grid 2048: nw = 8192 -> exactly 8 tiles/wave at B = 1M (no ragged tail).
    const int grid = 2048;
    fused_mfma_kernel<<<grid, 256, 0, stream>>>(x, ws, out, B, ntiles);
}